// Round 1
// baseline (68.234 us; speedup 1.0000x reference)
//
#include <hip/hip_runtime.h>
#include <math.h>

#define EPS 1e-6f

constexpr int BLOCK = 256;
constexpr int GRID  = 2048;

// Stage 1: per-block partial sums of k*dl*dl over all springs.
__global__ __launch_bounds__(BLOCK) void spring_energy_partial(
    const float* __restrict__ x,
    const float* __restrict__ l0,
    const float* __restrict__ k,
    const int*   __restrict__ idx,
    float* __restrict__ partials,
    int nsprings)
{
    const int tid      = blockIdx.x * BLOCK + threadIdx.x;
    const int nthreads = GRID * BLOCK;
    const int nquads   = nsprings >> 2;   // 4 springs per iteration

    float acc = 0.f;
    for (int q = tid; q < nquads; q += nthreads) {
        const int s = q << 2;
        // 16B vector loads: indices [E,2] row-major -> 8 ints per quad
        int4   ia  = *reinterpret_cast<const int4*>(idx + 2 * s);
        int4   ib  = *reinterpret_cast<const int4*>(idx + 2 * s + 4);
        float4 l0v = *reinterpret_cast<const float4*>(l0 + s);
        float4 kv  = *reinterpret_cast<const float4*>(k + s);

        const int   i1[4] = {ia.x, ia.z, ib.x, ib.z};
        const int   i2[4] = {ia.y, ia.w, ib.y, ib.w};
        const float lv[4] = {l0v.x, l0v.y, l0v.z, l0v.w};
        const float kvv[4]= {kv.x,  kv.y,  kv.z,  kv.w};

        #pragma unroll
        for (int j = 0; j < 4; ++j) {
            const float* p1 = x + 3 * i1[j];
            const float* p2 = x + 3 * i2[j];
            float dx = p1[0] - p2[0];
            float dy = p1[1] - p2[1];
            float dz = p1[2] - p2[2];
            float qd = dx*dx + dy*dy + dz*dz;
            float l  = sqrtf(qd + EPS);
            float dl = l - lv[j];
            acc = fmaf(kvv[j] * dl, dl, acc);
        }
    }

    // scalar tail (nsprings % 4), handled by block 0 only
    if (blockIdx.x == 0) {
        for (int s = (nquads << 2) + threadIdx.x; s < nsprings; s += BLOCK) {
            int i1 = idx[2 * s], i2 = idx[2 * s + 1];
            const float* p1 = x + 3 * i1;
            const float* p2 = x + 3 * i2;
            float dx = p1[0] - p2[0];
            float dy = p1[1] - p2[1];
            float dz = p1[2] - p2[2];
            float l  = sqrtf(dx*dx + dy*dy + dz*dz + EPS);
            float dl = l - l0[s];
            acc = fmaf(k[s] * dl, dl, acc);
        }
    }

    // wave (64-lane) reduction
    #pragma unroll
    for (int off = 32; off > 0; off >>= 1)
        acc += __shfl_down(acc, off, 64);

    __shared__ float wsum[BLOCK / 64];
    const int lane = threadIdx.x & 63;
    const int wid  = threadIdx.x >> 6;
    if (lane == 0) wsum[wid] = acc;
    __syncthreads();
    if (threadIdx.x == 0)
        partials[blockIdx.x] = wsum[0] + wsum[1] + wsum[2] + wsum[3];
}

// Stage 2: deterministic final reduction of GRID partials -> scalar energy.
__global__ __launch_bounds__(BLOCK) void spring_energy_final(
    const float* __restrict__ partials,
    float* __restrict__ out)
{
    float acc = 0.f;
    for (int i = threadIdx.x; i < GRID; i += BLOCK)
        acc += partials[i];

    #pragma unroll
    for (int off = 32; off > 0; off >>= 1)
        acc += __shfl_down(acc, off, 64);

    __shared__ float wsum[BLOCK / 64];
    const int lane = threadIdx.x & 63;
    const int wid  = threadIdx.x >> 6;
    if (lane == 0) wsum[wid] = acc;
    __syncthreads();
    if (threadIdx.x == 0)
        out[0] = 0.5f * (wsum[0] + wsum[1] + wsum[2] + wsum[3]);
}

extern "C" void kernel_launch(void* const* d_in, const int* in_sizes, int n_in,
                              void* d_out, int out_size, void* d_ws, size_t ws_size,
                              hipStream_t stream) {
    // setup_inputs() order: x [V,3] f32, l0 [E] f32, k [E] f32, indices [E,2] i32
    const float* x   = (const float*)d_in[0];
    const float* l0  = (const float*)d_in[1];
    const float* k   = (const float*)d_in[2];
    const int*   idx = (const int*)  d_in[3];
    float* out       = (float*)d_out;
    float* partials  = (float*)d_ws;   // GRID floats = 8 KB scratch

    const int nsprings = in_sizes[1];  // E = 6,400,000

    spring_energy_partial<<<GRID, BLOCK, 0, stream>>>(x, l0, k, idx, partials, nsprings);
    spring_energy_final<<<1, BLOCK, 0, stream>>>(partials, out);
}